// Round 6
// baseline (462.924 us; speedup 1.0000x reference)
//
#include <hip/hip_runtime.h>
#include <math.h>

#define BN 64
#define PN 16800
#define ON 64
#define THRESH 0.35f
#define NEGPOS 7
#define GX 66                  // encode blocks per row (66*256 >= 16800)
#define NBLK (BN * GX)         // 4224 partial slots
#define GXB 33                 // best_truth blocks per row (2 priors/thread, 512/block)
#define NBT (BN * GXB)         // 2112
#define NBP 1024               // best_prior blocks (64 rows x 16 groups of 4 truths)
#define K1_TOTAL (NBT + NBP)   // 3136
#define TG 4

// ---------- monotone float<->uint key ----------
__device__ __forceinline__ unsigned f2key(float f) {
  unsigned u = __float_as_uint(f);
  return (u & 0x80000000u) ? ~u : (u | 0x80000000u);
}
__device__ __forceinline__ float key2f(unsigned k) {
  unsigned u = (k & 0x80000000u) ? (k & 0x7FFFFFFFu) : ~k;
  return __uint_as_float(u);
}
__device__ __forceinline__ float sl1(float d) {
  float a = fabsf(d);
  return (a < 1.f) ? 0.5f * a * a : a - 0.5f;
}

// ================= K1: best_truth + best_prior + ticket-scatter =================
__global__ void k_match(const float* __restrict__ priors,
                        const float* __restrict__ targets,
                        float* __restrict__ bto, int* __restrict__ bti,
                        float* __restrict__ bpo, int* __restrict__ bpi,
                        unsigned* __restrict__ ticket) {
  int bid = blockIdx.x;
  int tid = threadIdx.x;
  __shared__ float si[TG][4], su[TG][4];
  __shared__ int spx[TG][4];
  __shared__ int lastFlag;

  if (bid < NBT) {
    // ---- best_truth: 2 priors/thread, truths via uniform (scalar) loads ----
    int b = bid / GXB;
    int xb = bid - b * GXB;
    int p0 = xb * 512 + tid;        // < PN always (block 32: <=16639)
    int p1 = p0 + 256;
    bool v1 = p1 < PN;
    float4 prA = reinterpret_cast<const float4*>(priors)[p0];
    float4 prB = reinterpret_cast<const float4*>(priors)[v1 ? p1 : p0];
    float px1A = prA.x - prA.z * 0.5f, py1A = prA.y - prA.w * 0.5f;
    float px2A = prA.x + prA.z * 0.5f, py2A = prA.y + prA.w * 0.5f;
    float abA = (px2A - px1A) * (py2A - py1A);
    float px1B = prB.x - prB.z * 0.5f, py1B = prB.y - prB.w * 0.5f;
    float px2B = prB.x + prB.z * 0.5f, py2B = prB.y + prB.w * 0.5f;
    float abB = (px2B - px1B) * (py2B - py1B);
    const float* tgb = &targets[(long)b * ON * 15];
    float biA = -1.f, buA = 1.f, biB = -1.f, buB = 1.f;
    int idA = 0, idB = 0;
#pragma unroll 16
    for (int t = 0; t < ON; t++) {
      float x1 = tgb[t * 15 + 0], y1 = tgb[t * 15 + 1];
      float x2 = tgb[t * 15 + 2], y2 = tgb[t * 15 + 3];   // uniform -> s_load
      float aa = (x2 - x1) * (y2 - y1);
      {
        float lx = fmaxf(x1, px1A), ly = fmaxf(y1, py1A);
        float rx = fminf(x2, px2A), ry = fminf(y2, py2A);
        float w = fmaxf(rx - lx, 0.f), h = fmaxf(ry - ly, 0.f);
        float inter = w * h;
        float uni = aa + abA - inter;
        if (inter * buA > biA * uni) { biA = inter; buA = uni; idA = t; }
      }
      {
        float lx = fmaxf(x1, px1B), ly = fmaxf(y1, py1B);
        float rx = fminf(x2, px2B), ry = fminf(y2, py2B);
        float w = fmaxf(rx - lx, 0.f), h = fmaxf(ry - ly, 0.f);
        float inter = w * h;
        float uni = aa + abB - inter;
        if (inter * buB > biB * uni) { biB = inter; buB = uni; idB = t; }
      }
    }
    bto[b * PN + p0] = biA / buA;
    bti[b * PN + p0] = idA;
    if (v1) {
      bto[b * PN + p1] = biB / buB;
      bti[b * PN + p1] = idB;
    }
  } else {
    // ---- best_prior: one block per (b, 4 truths) ----
    int id2 = bid - NBT;
    int b = id2 >> 4;
    int t0 = (id2 & 15) * TG;
    float ax1[TG], ay1[TG], ax2[TG], ay2[TG], area_a[TG];
#pragma unroll
    for (int i = 0; i < TG; i++) {
      const float* tg = &targets[((long)b * ON + t0 + i) * 15];
      ax1[i] = tg[0]; ay1[i] = tg[1]; ax2[i] = tg[2]; ay2[i] = tg[3];
      area_a[i] = (ax2[i] - ax1[i]) * (ay2[i] - ay1[i]);
    }
    float bi[TG], bu[TG]; int bp[TG];
#pragma unroll
    for (int i = 0; i < TG; i++) { bi[i] = -1.f; bu[i] = 1.f; bp[i] = 0x7FFFFFFF; }
    for (int p = tid; p < PN; p += 256) {
      float4 pr = reinterpret_cast<const float4*>(priors)[p];
      float px1 = pr.x - pr.z * 0.5f, py1 = pr.y - pr.w * 0.5f;
      float px2 = pr.x + pr.z * 0.5f, py2 = pr.y + pr.w * 0.5f;
      float area_b = (px2 - px1) * (py2 - py1);
#pragma unroll
      for (int i = 0; i < TG; i++) {
        float lx = fmaxf(ax1[i], px1), ly = fmaxf(ay1[i], py1);
        float rx = fminf(ax2[i], px2), ry = fminf(ay2[i], py2);
        float w = fmaxf(rx - lx, 0.f), h = fmaxf(ry - ly, 0.f);
        float inter = w * h;
        float uni = area_a[i] + area_b - inter;
        if (inter * bu[i] > bi[i] * uni) { bi[i] = inter; bu[i] = uni; bp[i] = p; }
      }
    }
#pragma unroll
    for (int off = 1; off < 64; off <<= 1) {
#pragma unroll
      for (int i = 0; i < TG; i++) {
        float oi = __shfl_xor(bi[i], off), ou = __shfl_xor(bu[i], off);
        int op = __shfl_xor(bp[i], off);
        float a = oi * bu[i], c = bi[i] * ou;
        if (a > c || (a == c && op < bp[i])) { bi[i] = oi; bu[i] = ou; bp[i] = op; }
      }
    }
    int w = tid >> 6;
    if ((tid & 63) == 0) {
#pragma unroll
      for (int i = 0; i < TG; i++) { si[i][w] = bi[i]; su[i][w] = bu[i]; spx[i][w] = bp[i]; }
    }
    __syncthreads();
    if (tid < TG) {
      float fi = si[tid][0], fu = su[tid][0]; int fp = spx[tid][0];
      for (int ww = 1; ww < 4; ww++) {
        float a = si[tid][ww] * fu, c = fi * su[tid][ww];
        if (a > c || (a == c && spx[tid][ww] < fp)) { fi = si[tid][ww]; fu = su[tid][ww]; fp = spx[tid][ww]; }
      }
      bpo[(long)b * ON + t0 + tid] = fi / fu;
      bpi[(long)b * ON + t0 + tid] = fp;
    }
  }

  // ---- ticket: last block performs the scatter fixups ----
  __threadfence();
  if (tid == 0) {
    unsigned old = atomicAdd(ticket, 1u);
    lastFlag = (old == (unsigned)(K1_TOTAL - 1)) ? 1 : 0;
  }
  __syncthreads();
  if (lastFlag) {
    __threadfence();
    int lane = tid & 63;
    int w = tid >> 6;
    for (int g = 0; g < 16; g++) {
      int row = g * 4 + w;
      int q = bpi[row * ON + lane];
      float ov = bpo[row * ON + lane];
      bool valid = ov >= 0.2f;
      bool dupLater = false;
      for (int j = 0; j < 64; j++) {
        int ij = __shfl(q, j);
        if (j > lane && ij == q) dupLater = true;
      }
      if (!dupLater) {
        bti[(long)row * PN + q] = lane;          // last-write-wins winner
        if (valid) bto[(long)row * PN + q] = 2.0f;
      }
    }
  }
}

// ================= K2: encode + smooth-l1 + loss_c + per-block partials =================
__global__ void k_encode(const float* __restrict__ loc_data,
                         const float* __restrict__ conf_data,
                         const float* __restrict__ landm_data,
                         const float* __restrict__ priors,
                         const float* __restrict__ targets,
                         const float* __restrict__ bto, const int* __restrict__ bti,
                         float* __restrict__ lossc, unsigned char* __restrict__ posf,
                         float* __restrict__ part_l, float* __restrict__ part_lm,
                         int* __restrict__ np_part, int* __restrict__ np1_part) {
  int b = blockIdx.y;
  int p = blockIdx.x * 256 + threadIdx.x;
  int bid = b * GX + blockIdx.x;
  __shared__ float tgs[ON * 15];
  for (int i = threadIdx.x; i < ON * 15; i += 256)
    tgs[i] = targets[(long)b * ON * 15 + i];
  __syncthreads();
  float sum_l = 0.f, sum_lm = 0.f;
  int cp = 0, cp1 = 0;
  if (p < PN) {
    int t = bti[b * PN + p];
    float ov = bto[b * PN + p];
    const float* tg = &tgs[t * 15];
    float label = tg[14];
    bool pos = ov >= THRESH;            // label is +-1, never 0
    bool pos1 = pos && (label > 0.f);
    float4 pr = reinterpret_cast<const float4*>(priors)[p];
    if (pos) {
      float rz = 1.0f / pr.z, rw = 1.0f / pr.w;   // 2 divides total
      float m0 = tg[0], m1 = tg[1], m2 = tg[2], m3 = tg[3];
      float g0 = ((m0 + m2) * 0.5f - pr.x) * rz * 10.f;
      float g1 = ((m1 + m3) * 0.5f - pr.y) * rw * 10.f;
      float g2 = __logf((m2 - m0) * rz) * 5.f;
      float g3 = __logf((m3 - m1) * rw) * 5.f;
      const float* ld = &loc_data[((long)b * PN + p) * 4];
      sum_l = sl1(ld[0] - g0) + sl1(ld[1] - g1) + sl1(ld[2] - g2) + sl1(ld[3] - g3);
      cp = 1;
      if (pos1) {
        const float* lm = &landm_data[((long)b * PN + p) * 10];
#pragma unroll
        for (int i = 0; i < 5; i++) {
          float gx = (tg[4 + 2 * i] - pr.x) * rz * 10.f;
          float gy = (tg[5 + 2 * i] - pr.y) * rw * 10.f;
          sum_lm += sl1(lm[2 * i] - gx) + sl1(lm[2 * i + 1] - gy);
        }
        cp1 = 1;
      }
    }
    float2 c2 = reinterpret_cast<const float2*>(conf_data)[(long)b * PN + p];
    float m = fmaxf(c2.x, c2.y);
    float lse = m + __logf(__expf(c2.x - m) + __expf(c2.y - m));  // shift-invariant
    lossc[b * PN + p] = lse - (pos ? c2.y : c2.x);
    posf[b * PN + p] = pos ? 1 : 0;
  }
  for (int off = 32; off; off >>= 1) {
    sum_l += __shfl_down(sum_l, off);
    sum_lm += __shfl_down(sum_lm, off);
    cp += __shfl_down(cp, off);
    cp1 += __shfl_down(cp1, off);
  }
  __shared__ float sl4[4], slm4[4];
  __shared__ int sp4[4], sp14[4];
  int w = threadIdx.x >> 6;
  if ((threadIdx.x & 63) == 0) { sl4[w] = sum_l; slm4[w] = sum_lm; sp4[w] = cp; sp14[w] = cp1; }
  __syncthreads();
  if (threadIdx.x == 0) {
    part_l[bid] = sl4[0] + sl4[1] + sl4[2] + sl4[3];
    part_lm[bid] = slm4[0] + slm4[1] + slm4[2] + slm4[3];
    np_part[bid] = sp4[0] + sp4[1] + sp4[2] + sp4[3];
    np1_part[bid] = sp14[0] + sp14[1] + sp14[2] + sp14[3];
  }
}

// ================= K3: radix select (12/10/10) + fused CE sum + ticket-final =================
__global__ void __launch_bounds__(1024) k_select(const float* __restrict__ lossc,
                                                 const unsigned char* __restrict__ posf,
                                                 const int* __restrict__ np_part,
                                                 const int* __restrict__ np1_part,
                                                 const float* __restrict__ part_l,
                                                 const float* __restrict__ part_lm,
                                                 float* __restrict__ part_c,
                                                 unsigned* __restrict__ ticket,
                                                 float* __restrict__ out) {
  int b = blockIdx.x;
  int tid = threadIdx.x;
  __shared__ unsigned bins[4096];
  __shared__ unsigned gs[1025];
  __shared__ unsigned s_d, s_rem;
  __shared__ int s_np;
  __shared__ int lastF;
  const float* row = &lossc[(long)b * PN];
  const unsigned char* prow = &posf[(long)b * PN];

  if (tid == 0) s_np = 0;
  __syncthreads();
  if (tid < GX) atomicAdd(&s_np, np_part[b * GX + tid]);
  __syncthreads();
  int np = s_np;
  int k = NEGPOS * np;
  if (k > PN - 1) k = PN - 1;
  bool haveNeg = (k > 0);

  unsigned T = 0, R = 0, C = 0;
  if (haveNeg) {
    unsigned rem = (unsigned)k;
    // ---- pass 0: bits [31:20], 4096 bins ----
    for (int i = tid; i < 4096; i += 1024) bins[i] = 0;
    __syncthreads();
    for (int p = tid; p < PN; p += 1024) atomicAdd(&bins[f2key(row[p]) >> 20], 1u);
    __syncthreads();
    unsigned l0 = bins[4 * tid], l1 = bins[4 * tid + 1], l2 = bins[4 * tid + 2], l3 = bins[4 * tid + 3];
    gs[tid] = l0 + l1 + l2 + l3;
    if (tid == 0) gs[1024] = 0;
    __syncthreads();
    for (int off = 1; off < 1024; off <<= 1) {
      unsigned v = (tid + off < 1024) ? gs[tid + off] : 0;
      __syncthreads();
      gs[tid] += v;
      __syncthreads();
    }
    {
      unsigned nx = gs[tid + 1];
      if (gs[tid] >= rem && nx < rem) {
        unsigned run = nx, cc; int d;
        if (run + l3 >= rem) { d = 3; cc = l3; }
        else { run += l3;
          if (run + l2 >= rem) { d = 2; cc = l2; }
          else { run += l2;
            if (run + l1 >= rem) { d = 1; cc = l1; }
            else { run += l1; d = 0; cc = l0; } } }
        (void)cc;
        s_d = 4 * (unsigned)tid + (unsigned)d;
        s_rem = rem - run;
      }
    }
    __syncthreads();
    unsigned d0 = s_d; rem = s_rem;
    __syncthreads();
    // ---- pass 1: bits [19:10] ----
    bins[tid] = 0;
    __syncthreads();
    for (int p = tid; p < PN; p += 1024) {
      unsigned key = f2key(row[p]);
      if ((key >> 20) == d0) atomicAdd(&bins[(key >> 10) & 1023], 1u);
    }
    __syncthreads();
    gs[tid] = bins[tid];
    if (tid == 0) gs[1024] = 0;
    __syncthreads();
    for (int off = 1; off < 1024; off <<= 1) {
      unsigned v = (tid + off < 1024) ? gs[tid + off] : 0;
      __syncthreads();
      gs[tid] += v;
      __syncthreads();
    }
    {
      unsigned nx = gs[tid + 1];
      if (gs[tid] >= rem && nx < rem) { s_d = (unsigned)tid; s_rem = rem - nx; }
    }
    __syncthreads();
    unsigned d1 = s_d; rem = s_rem;
    unsigned pref = (d0 << 10) | d1;
    __syncthreads();
    // ---- pass 2: bits [9:0] ----
    bins[tid] = 0;
    __syncthreads();
    for (int p = tid; p < PN; p += 1024) {
      unsigned key = f2key(row[p]);
      if ((key >> 10) == pref) atomicAdd(&bins[key & 1023], 1u);
    }
    __syncthreads();
    gs[tid] = bins[tid];
    if (tid == 0) gs[1024] = 0;
    __syncthreads();
    for (int off = 1; off < 1024; off <<= 1) {
      unsigned v = (tid + off < 1024) ? gs[tid + off] : 0;
      __syncthreads();
      gs[tid] += v;
      __syncthreads();
    }
    {
      unsigned nx = gs[tid + 1];
      if (gs[tid] >= rem && nx < rem) { s_d = (unsigned)tid; s_rem = rem - nx; }
    }
    __syncthreads();
    unsigned d2 = s_d;
    R = s_rem;
    C = bins[d2];
    T = (pref << 10) | d2;
  }

  // ---- fused sum: S_pos + S_{key>T, !pos} (+ ties) ----
  float acc = 0.f;
  unsigned ptc = 0;   // pos elements with key == T
  for (int p = tid; p < PN; p += 1024) {
    float v = row[p];
    bool pos = prow[p] != 0;
    unsigned key = f2key(v);
    if (pos) acc += v;
    else if (haveNeg && key > T) acc += v;
    if (haveNeg && pos && key == T) ptc++;
  }
  if (haveNeg && C != R && tid < 64) {
    // rare: more ties than slots -> rank ties by index (stable argsort tiebreak)
    unsigned running = 0;
    for (int base = 0; base < PN; base += 64) {
      int p = base + tid;
      bool tie = false, pos = false;
      float v = 0.f;
      if (p < PN) { v = row[p]; tie = (f2key(v) == T); pos = prow[p] != 0; }
      unsigned long long m = __ballot(tie);
      if (tie) {
        unsigned rank = running + (unsigned)__popcll(m & ((1ull << tid) - 1));
        if (rank < R && !pos) acc += v;
      }
      running += (unsigned)__popcll(m);
    }
  }
  for (int off = 32; off; off >>= 1) {
    acc += __shfl_down(acc, off);
    ptc += __shfl_down(ptc, off);
  }
  __shared__ float wsum[16];
  __shared__ unsigned wpt[16];
  if ((tid & 63) == 0) { wsum[tid >> 6] = acc; wpt[tid >> 6] = ptc; }
  __syncthreads();
  if (tid == 0) {
    float tot = 0.f; unsigned pt = 0;
    for (int i = 0; i < 16; i++) { tot += wsum[i]; pt += wpt[i]; }
    if (haveNeg && C == R) tot += (float)(C - pt) * key2f(T);  // all ties selected; equal values
    part_c[b] = tot;
  }

  // ---- ticket: last block reduces everything to the 3 outputs ----
  __threadfence();
  if (tid == 0) lastF = (atomicAdd(ticket, 1u) == (unsigned)(BN - 1)) ? 1 : 0;
  __syncthreads();
  if (lastF) {
    __threadfence();
    float sl = 0.f, slm = 0.f, sc = 0.f;
    int npT = 0, np1T = 0;
    for (int i = tid; i < NBLK; i += 1024) {
      sl += part_l[i]; slm += part_lm[i];
      npT += np_part[i]; np1T += np1_part[i];
    }
    if (tid < BN) sc = part_c[tid];
    for (int off = 32; off; off >>= 1) {
      sl += __shfl_down(sl, off); slm += __shfl_down(slm, off); sc += __shfl_down(sc, off);
      npT += __shfl_down(npT, off); np1T += __shfl_down(np1T, off);
    }
    __shared__ float fa[16], fb[16], fc[16];
    __shared__ int ia[16], ib[16];
    if ((tid & 63) == 0) { fa[tid >> 6] = sl; fb[tid >> 6] = slm; fc[tid >> 6] = sc; ia[tid >> 6] = npT; ib[tid >> 6] = np1T; }
    __syncthreads();
    if (tid == 0) {
      float tsl = 0, tslm = 0, tsc = 0; int tnp = 0, tnp1 = 0;
      for (int i = 0; i < 16; i++) { tsl += fa[i]; tslm += fb[i]; tsc += fc[i]; tnp += ia[i]; tnp1 += ib[i]; }
      float N = fmaxf((float)tnp, 1.f);
      float N1 = fmaxf((float)tnp1, 1.f);
      out[0] = tsl / N;
      out[1] = tsc / N;
      out[2] = tslm / N1;
    }
  }
}

extern "C" void kernel_launch(void* const* d_in, const int* in_sizes, int n_in,
                              void* d_out, int out_size, void* d_ws, size_t ws_size,
                              hipStream_t stream) {
  const float* loc_data = (const float*)d_in[0];
  const float* conf_data = (const float*)d_in[1];
  const float* landm_data = (const float*)d_in[2];
  const float* priors = (const float*)d_in[3];
  const float* targets = (const float*)d_in[4];
  float* out = (float*)d_out;

  char* ws = (char*)d_ws;
  const size_t SZ = (size_t)BN * PN * 4;
  size_t off = 0;
  float* lossc = (float*)(ws + off); off += SZ;
  float* bto = (float*)(ws + off); off += SZ;
  int* bti = (int*)(ws + off); off += SZ;
  unsigned char* posf = (unsigned char*)(ws + off); off += (size_t)BN * PN;
  off = (off + 15) & ~(size_t)15;
  float* bpo = (float*)(ws + off); off += (size_t)BN * ON * 4;
  int* bpi = (int*)(ws + off); off += (size_t)BN * ON * 4;
  float* part_l = (float*)(ws + off); off += NBLK * 4;
  float* part_lm = (float*)(ws + off); off += NBLK * 4;
  float* part_c = (float*)(ws + off); off += BN * 4;
  int* np_part = (int*)(ws + off); off += NBLK * 4;
  int* np1_part = (int*)(ws + off); off += NBLK * 4;
  unsigned* tickets = (unsigned*)(ws + off); off += 2 * sizeof(unsigned);

  hipMemsetAsync(tickets, 0, 2 * sizeof(unsigned), stream);

  k_match<<<K1_TOTAL, 256, 0, stream>>>(priors, targets, bto, bti, bpo, bpi, &tickets[0]);
  dim3 gbp(GX, BN);
  k_encode<<<gbp, 256, 0, stream>>>(loc_data, conf_data, landm_data, priors, targets,
                                    bto, bti, lossc, posf,
                                    part_l, part_lm, np_part, np1_part);
  k_select<<<BN, 1024, 0, stream>>>(lossc, posf, np_part, np1_part, part_l, part_lm,
                                    part_c, &tickets[1], out);
}

// Round 7
// 222.693 us; speedup vs baseline: 2.0788x; 2.0788x over previous
//
#include <hip/hip_runtime.h>
#include <math.h>

#define BN 64
#define PN 16800
#define ON 64
#define THRESH 0.35f
#define NEGPOS 7
#define GX 66                  // encode blocks per row (66*256 >= 16800)
#define NBLK (BN * GX)         // 4224 partial slots
#define GXB 17                 // best_truth blocks per row (1024 priors/block, 4/thread)
#define PT 4                   // priors per thread in best_truth
#define TG 4                   // truths per block in best_prior

// ---------- monotone float<->uint key ----------
__device__ __forceinline__ unsigned f2key(float f) {
  unsigned u = __float_as_uint(f);
  return (u & 0x80000000u) ? ~u : (u | 0x80000000u);
}
__device__ __forceinline__ float key2f(unsigned k) {
  unsigned u = (k & 0x80000000u) ? (k & 0x7FFFFFFFu) : ~k;
  return __uint_as_float(u);
}
__device__ __forceinline__ float sl1(float d) {
  float a = fabsf(d);
  return (a < 1.f) ? 0.5f * a * a : a - 0.5f;
}

// ================= K1: per-prior best truth (LDS truths, 4 priors/thread) =================
__global__ void k_best_truth(const float* __restrict__ priors,
                             const float* __restrict__ targets,
                             float* __restrict__ bto, int* __restrict__ bti) {
  int b = blockIdx.y;
  int tid = threadIdx.x;
  int base = blockIdx.x * 1024 + tid;   // base < PN always (block 16: <=16639)

  __shared__ float4 tbox[ON];
  __shared__ float tarea[ON];
  if (tid < ON) {
    const float* tg = &targets[((long)b * ON + tid) * 15];
    float4 bx = make_float4(tg[0], tg[1], tg[2], tg[3]);
    tbox[tid] = bx;
    tarea[tid] = (bx.z - bx.x) * (bx.w - bx.y);
  }
  __syncthreads();

  float px1[PT], py1[PT], px2[PT], py2[PT], ab[PT];
  bool val[PT];
#pragma unroll
  for (int i = 0; i < PT; i++) {
    int p = base + 256 * i;
    val[i] = p < PN;
    float4 pr = reinterpret_cast<const float4*>(priors)[val[i] ? p : base];
    px1[i] = pr.x - pr.z * 0.5f; py1[i] = pr.y - pr.w * 0.5f;
    px2[i] = pr.x + pr.z * 0.5f; py2[i] = pr.y + pr.w * 0.5f;
    ab[i] = (px2[i] - px1[i]) * (py2[i] - py1[i]);
  }
  float bi[PT], bu[PT]; int id[PT];
#pragma unroll
  for (int i = 0; i < PT; i++) { bi[i] = -1.f; bu[i] = 1.f; id[i] = 0; }

#pragma unroll 4
  for (int t = 0; t < ON; t++) {
    float4 a = tbox[t];
    float aa = tarea[t];
#pragma unroll
    for (int i = 0; i < PT; i++) {
      float lx = fmaxf(a.x, px1[i]), ly = fmaxf(a.y, py1[i]);
      float rx = fminf(a.z, px2[i]), ry = fminf(a.w, py2[i]);
      float w = fmaxf(rx - lx, 0.f), h = fmaxf(ry - ly, 0.f);
      float inter = w * h;
      float uni = aa + ab[i] - inter;
      // inter/uni > bi/bu  <=>  inter*bu > bi*uni  (both denominators > 0)
      if (inter * bu[i] > bi[i] * uni) { bi[i] = inter; bu[i] = uni; id[i] = t; }
    }
  }
#pragma unroll
  for (int i = 0; i < PT; i++) {
    if (val[i]) {
      int p = base + 256 * i;
      bto[(long)b * PN + p] = bi[i] / bu[i];   // single division, same operands as ref
      bti[(long)b * PN + p] = id[i];
    }
  }
}

// ================= K2: per-truth best prior (one block per (b, 4 truths)) =================
__global__ void k_best_prior(const float* __restrict__ priors,
                             const float* __restrict__ targets,
                             float* __restrict__ bpo, int* __restrict__ bpi) {
  int bx = blockIdx.x;
  int b = bx >> 4;
  int t0 = (bx & 15) * TG;
  int tid = threadIdx.x;
  float ax1[TG], ay1[TG], ax2[TG], ay2[TG], area_a[TG];
#pragma unroll
  for (int i = 0; i < TG; i++) {
    const float* tg = &targets[((long)b * ON + t0 + i) * 15];
    ax1[i] = tg[0]; ay1[i] = tg[1]; ax2[i] = tg[2]; ay2[i] = tg[3];
    area_a[i] = (ax2[i] - ax1[i]) * (ay2[i] - ay1[i]);
  }
  float bi[TG], bu[TG]; int bp[TG];
#pragma unroll
  for (int i = 0; i < TG; i++) { bi[i] = -1.f; bu[i] = 1.f; bp[i] = 0x7FFFFFFF; }
  for (int p = tid; p < PN; p += 256) {
    float4 pr = reinterpret_cast<const float4*>(priors)[p];
    float px1 = pr.x - pr.z * 0.5f, py1 = pr.y - pr.w * 0.5f;
    float px2 = pr.x + pr.z * 0.5f, py2 = pr.y + pr.w * 0.5f;
    float area_b = (px2 - px1) * (py2 - py1);
#pragma unroll
    for (int i = 0; i < TG; i++) {
      float lx = fmaxf(ax1[i], px1), ly = fmaxf(ay1[i], py1);
      float rx = fminf(ax2[i], px2), ry = fminf(ay2[i], py2);
      float w = fmaxf(rx - lx, 0.f), h = fmaxf(ry - ly, 0.f);
      float inter = w * h;
      float uni = area_a[i] + area_b - inter;
      if (inter * bu[i] > bi[i] * uni) { bi[i] = inter; bu[i] = uni; bp[i] = p; }
    }
  }
#pragma unroll
  for (int off = 1; off < 64; off <<= 1) {
#pragma unroll
    for (int i = 0; i < TG; i++) {
      float oi = __shfl_xor(bi[i], off), ou = __shfl_xor(bu[i], off);
      int op = __shfl_xor(bp[i], off);
      float a = oi * bu[i], c = bi[i] * ou;
      if (a > c || (a == c && op < bp[i])) { bi[i] = oi; bu[i] = ou; bp[i] = op; }
    }
  }
  __shared__ float si[TG][4], su[TG][4];
  __shared__ int spx[TG][4];
  int w = tid >> 6;
  if ((tid & 63) == 0) {
#pragma unroll
    for (int i = 0; i < TG; i++) { si[i][w] = bi[i]; su[i][w] = bu[i]; spx[i][w] = bp[i]; }
  }
  __syncthreads();
  if (tid < TG) {
    float fi = si[tid][0], fu = su[tid][0]; int fp = spx[tid][0];
    for (int ww = 1; ww < 4; ww++) {
      float a = si[tid][ww] * fu, c = fi * su[tid][ww];
      if (a > c || (a == c && spx[tid][ww] < fp)) { fi = si[tid][ww]; fu = su[tid][ww]; fp = spx[tid][ww]; }
    }
    bpo[(long)b * ON + t0 + tid] = fi / fu;
    bpi[(long)b * ON + t0 + tid] = fp;
  }
}

// ================= K3: parallel scatter fixups (last-write-wins winners) =================
__global__ void k_scatter(const float* __restrict__ bpo, const int* __restrict__ bpi,
                          float* __restrict__ bto, int* __restrict__ bti) {
  int tid = threadIdx.x;
  int row = blockIdx.x * 4 + (tid >> 6);   // 16 blocks x 4 rows
  int t = tid & 63;
  int q = bpi[row * ON + t];
  bool valid = bpo[row * ON + t] >= 0.2f;
  bool dupLater = false;
  for (int j = 0; j < 64; j++) {
    int ij = __shfl(q, j);
    if (j > t && ij == q) dupLater = true;
  }
  if (!dupLater) {
    bti[(long)row * PN + q] = t;               // unconditional arange write
    if (valid) bto[(long)row * PN + q] = 2.0f; // non-valid keeps original: no-op
  }
}

// ================= K4: encode + smooth-l1 + loss_c + per-block partials =================
__global__ void k_encode(const float* __restrict__ loc_data,
                         const float* __restrict__ conf_data,
                         const float* __restrict__ landm_data,
                         const float* __restrict__ priors,
                         const float* __restrict__ targets,
                         const float* __restrict__ bto, const int* __restrict__ bti,
                         float* __restrict__ lossc, unsigned char* __restrict__ posf,
                         float* __restrict__ part_l, float* __restrict__ part_lm,
                         int* __restrict__ np_part, int* __restrict__ np1_part) {
  int b = blockIdx.y;
  int p = blockIdx.x * 256 + threadIdx.x;
  int bid = b * GX + blockIdx.x;
  __shared__ float4 tgs4[ON * 15 / 4];     // 240 float4 = 960 floats
  float* tgs = (float*)tgs4;
  if (threadIdx.x < ON * 15 / 4)
    tgs4[threadIdx.x] = reinterpret_cast<const float4*>(targets + (long)b * ON * 15)[threadIdx.x];
  __syncthreads();
  float sum_l = 0.f, sum_lm = 0.f;
  int cp = 0, cp1 = 0;
  if (p < PN) {
    int t = bti[b * PN + p];
    float ov = bto[b * PN + p];
    const float* tg = &tgs[t * 15];
    float label = tg[14];
    bool pos = ov >= THRESH;            // label is +-1, never 0
    bool pos1 = pos && (label > 0.f);
    float4 pr = reinterpret_cast<const float4*>(priors)[p];
    if (pos) {
      float rz = 1.0f / pr.z, rw = 1.0f / pr.w;   // 2 divides total
      float m0 = tg[0], m1 = tg[1], m2 = tg[2], m3 = tg[3];
      float g0 = ((m0 + m2) * 0.5f - pr.x) * rz * 10.f;
      float g1 = ((m1 + m3) * 0.5f - pr.y) * rw * 10.f;
      float g2 = __logf((m2 - m0) * rz) * 5.f;
      float g3 = __logf((m3 - m1) * rw) * 5.f;
      const float* ld = &loc_data[((long)b * PN + p) * 4];
      sum_l = sl1(ld[0] - g0) + sl1(ld[1] - g1) + sl1(ld[2] - g2) + sl1(ld[3] - g3);
      cp = 1;
      if (pos1) {
        const float* lm = &landm_data[((long)b * PN + p) * 10];
#pragma unroll
        for (int i = 0; i < 5; i++) {
          float gx = (tg[4 + 2 * i] - pr.x) * rz * 10.f;
          float gy = (tg[5 + 2 * i] - pr.y) * rw * 10.f;
          sum_lm += sl1(lm[2 * i] - gx) + sl1(lm[2 * i + 1] - gy);
        }
        cp1 = 1;
      }
    }
    float2 c2 = reinterpret_cast<const float2*>(conf_data)[(long)b * PN + p];
    float m = fmaxf(c2.x, c2.y);
    float lse = m + __logf(__expf(c2.x - m) + __expf(c2.y - m));  // shift-invariant
    lossc[b * PN + p] = lse - (pos ? c2.y : c2.x);
    posf[b * PN + p] = pos ? 1 : 0;
  }
  for (int off = 32; off; off >>= 1) {
    sum_l += __shfl_down(sum_l, off);
    sum_lm += __shfl_down(sum_lm, off);
    cp += __shfl_down(cp, off);
    cp1 += __shfl_down(cp1, off);
  }
  __shared__ float sl4[4], slm4[4];
  __shared__ int sp4[4], sp14[4];
  int w = threadIdx.x >> 6;
  if ((threadIdx.x & 63) == 0) { sl4[w] = sum_l; slm4[w] = sum_lm; sp4[w] = cp; sp14[w] = cp1; }
  __syncthreads();
  if (threadIdx.x == 0) {
    part_l[bid] = sl4[0] + sl4[1] + sl4[2] + sl4[3];
    part_lm[bid] = slm4[0] + slm4[1] + slm4[2] + slm4[3];
    np_part[bid] = sp4[0] + sp4[1] + sp4[2] + sp4[3];
    np1_part[bid] = sp14[0] + sp14[1] + sp14[2] + sp14[3];
  }
}

// ================= K5: radix select (4x8-bit, wave-scan) + fused CE sum =================
__global__ void __launch_bounds__(1024) k_select(const float* __restrict__ lossc,
                                                 const unsigned char* __restrict__ posf,
                                                 const int* __restrict__ np_part,
                                                 float* __restrict__ part_c) {
  int b = blockIdx.x;
  int tid = threadIdx.x;
  __shared__ unsigned hist[256];
  __shared__ unsigned wtot[4];
  __shared__ unsigned s_d, s_rem;
  __shared__ int s_np;
  const float* row = &lossc[(long)b * PN];
  const unsigned char* prow = &posf[(long)b * PN];

  if (tid == 0) s_np = 0;
  __syncthreads();
  if (tid < GX) atomicAdd(&s_np, np_part[b * GX + tid]);
  __syncthreads();
  int k = NEGPOS * s_np;
  if (k > PN - 1) k = PN - 1;
  bool haveNeg = (k > 0);

  unsigned T = 0, R = 0, C = 0;
  if (haveNeg) {
    unsigned rem = (unsigned)k, prefix = 0;
    for (int pass = 0; pass < 4; pass++) {
      int shift = 24 - pass * 8;
      if (tid < 256) hist[tid] = 0;
      __syncthreads();
      unsigned hmask = (pass == 0) ? 0u : (0xFFFFFFFFu << (shift + 8));
      for (int p = tid; p < PN; p += 1024) {
        unsigned key = f2key(row[p]);
        if (((key ^ prefix) & hmask) == 0)
          atomicAdd(&hist[(key >> shift) & 255], 1u);
      }
      __syncthreads();
      // hierarchical suffix scan: 4 waves x 64 bins (shfl) + wave totals
      unsigned h = (tid < 256) ? hist[tid] : 0;
      unsigned v = h;
      int lane = tid & 63;
#pragma unroll
      for (int off = 1; off < 64; off <<= 1) {
        unsigned tv = (unsigned)__shfl_down((int)v, off);
        if (lane + off < 64) v += tv;
      }
      if (tid < 256 && lane == 0) wtot[tid >> 6] = v;   // wave-segment total
      __syncthreads();
      if (tid < 256) {
        unsigned add = 0;
        for (int w2 = (tid >> 6) + 1; w2 < 4; w2++) add += wtot[w2];
        unsigned suf = v + add;                  // count of keys with digit >= tid
        if (suf >= rem && (suf - h) < rem) { s_d = (unsigned)tid; s_rem = rem - (suf - h); }
      }
      __syncthreads();
      prefix |= s_d << shift;
      rem = s_rem;
      if (pass == 3) { T = prefix; R = rem; C = hist[s_d]; }
      __syncthreads();
    }
  }

  // ---- fused sum: S_pos + S_{key>T, !pos} (+ ties) ----
  float acc = 0.f;
  unsigned ptc = 0;   // pos elements with key == T
  for (int p = tid; p < PN; p += 1024) {
    float v = row[p];
    bool pos = prow[p] != 0;
    unsigned key = f2key(v);
    if (pos) acc += v;
    else if (haveNeg && key > T) acc += v;
    if (haveNeg && pos && key == T) ptc++;
  }
  if (haveNeg && C != R && tid < 64) {
    // rare: more ties than slots -> rank ties by index (stable argsort tiebreak)
    unsigned running = 0;
    for (int base = 0; base < PN; base += 64) {
      int p = base + tid;
      bool tie = false, pos = false;
      float v = 0.f;
      if (p < PN) { v = row[p]; tie = (f2key(v) == T); pos = prow[p] != 0; }
      unsigned long long m = __ballot(tie);
      if (tie) {
        unsigned rank = running + (unsigned)__popcll(m & ((1ull << tid) - 1));
        if (rank < R && !pos) acc += v;
      }
      running += (unsigned)__popcll(m);
    }
  }
  for (int off = 32; off; off >>= 1) {
    acc += __shfl_down(acc, off);
    ptc += __shfl_down(ptc, off);
  }
  __shared__ float wsum[16];
  __shared__ unsigned wpt[16];
  if ((tid & 63) == 0) { wsum[tid >> 6] = acc; wpt[tid >> 6] = ptc; }
  __syncthreads();
  if (tid == 0) {
    float tot = 0.f; unsigned pt = 0;
    for (int i = 0; i < 16; i++) { tot += wsum[i]; pt += wpt[i]; }
    if (haveNeg && C == R) tot += (float)(C - pt) * key2f(T);  // all ties selected; equal values
    part_c[b] = tot;
  }
}

// ================= K6: reduce all partials, finalize three scalars =================
__global__ void k_final(const float* __restrict__ part_l, const float* __restrict__ part_lm,
                        const float* __restrict__ part_c,
                        const int* __restrict__ np_part, const int* __restrict__ np1_part,
                        float* __restrict__ out) {
  float sl = 0.f, slm = 0.f, sc = 0.f;
  int np = 0, np1 = 0;
  for (int i = threadIdx.x; i < NBLK; i += 256) {
    sl += part_l[i]; slm += part_lm[i];
    np += np_part[i]; np1 += np1_part[i];
  }
  if (threadIdx.x < BN) sc = part_c[threadIdx.x];
  for (int off = 32; off; off >>= 1) {
    sl += __shfl_down(sl, off); slm += __shfl_down(slm, off); sc += __shfl_down(sc, off);
    np += __shfl_down(np, off); np1 += __shfl_down(np1, off);
  }
  __shared__ float a[4], bsh[4], c[4];
  __shared__ int d[4], e[4];
  int w = threadIdx.x >> 6;
  if ((threadIdx.x & 63) == 0) { a[w] = sl; bsh[w] = slm; c[w] = sc; d[w] = np; e[w] = np1; }
  __syncthreads();
  if (threadIdx.x == 0) {
    float N = fmaxf((float)(d[0] + d[1] + d[2] + d[3]), 1.f);
    float N1 = fmaxf((float)(e[0] + e[1] + e[2] + e[3]), 1.f);
    out[0] = (a[0] + a[1] + a[2] + a[3]) / N;
    out[1] = (c[0] + c[1] + c[2] + c[3]) / N;
    out[2] = (bsh[0] + bsh[1] + bsh[2] + bsh[3]) / N1;
  }
}

extern "C" void kernel_launch(void* const* d_in, const int* in_sizes, int n_in,
                              void* d_out, int out_size, void* d_ws, size_t ws_size,
                              hipStream_t stream) {
  const float* loc_data = (const float*)d_in[0];
  const float* conf_data = (const float*)d_in[1];
  const float* landm_data = (const float*)d_in[2];
  const float* priors = (const float*)d_in[3];
  const float* targets = (const float*)d_in[4];
  float* out = (float*)d_out;

  char* ws = (char*)d_ws;
  const size_t SZ = (size_t)BN * PN * 4;
  size_t off = 0;
  float* lossc = (float*)(ws + off); off += SZ;
  float* bto = (float*)(ws + off); off += SZ;
  int* bti = (int*)(ws + off); off += SZ;
  unsigned char* posf = (unsigned char*)(ws + off); off += (size_t)BN * PN;
  off = (off + 15) & ~(size_t)15;
  float* bpo = (float*)(ws + off); off += (size_t)BN * ON * 4;
  int* bpi = (int*)(ws + off); off += (size_t)BN * ON * 4;
  float* part_l = (float*)(ws + off); off += NBLK * 4;
  float* part_lm = (float*)(ws + off); off += NBLK * 4;
  float* part_c = (float*)(ws + off); off += BN * 4;
  int* np_part = (int*)(ws + off); off += NBLK * 4;
  int* np1_part = (int*)(ws + off); off += NBLK * 4;

  dim3 gbt(GXB, BN);
  dim3 gbp(GX, BN);

  k_best_truth<<<gbt, 256, 0, stream>>>(priors, targets, bto, bti);
  k_best_prior<<<BN * (ON / TG), 256, 0, stream>>>(priors, targets, bpo, bpi);
  k_scatter<<<16, 256, 0, stream>>>(bpo, bpi, bto, bti);
  k_encode<<<gbp, 256, 0, stream>>>(loc_data, conf_data, landm_data, priors, targets,
                                    bto, bti, lossc, posf,
                                    part_l, part_lm, np_part, np1_part);
  k_select<<<BN, 1024, 0, stream>>>(lossc, posf, np_part, part_c);
  k_final<<<1, 256, 0, stream>>>(part_l, part_lm, part_c, np_part, np1_part, out);
}